// Round 2
// baseline (4702.958 us; speedup 1.0000x reference)
//
#include <hip/hip_runtime.h>
#include <stdint.h>

typedef _Float16 f16;
typedef _Float16 f16x8 __attribute__((ext_vector_type(8)));
typedef float f32x4 __attribute__((ext_vector_type(4)));

#define NROWS 16384
#define DIM   512
#define NEXP  8
#define BM    128
#define BN    64
#define BK    32
#define KSTEPS (DIM/BK)
#define WSTRIDE (DIM*DIM)

// async global->LDS, 16B per lane, LDS dest = wave-uniform base + lane*16
#define GLOAD16(gp, lp) __builtin_amdgcn_global_load_lds( \
    (const __attribute__((address_space(1))) void*)(gp),  \
    (__attribute__((address_space(3))) void*)(lp), 16, 0, 0)

// ---------- prep: W[l][e][i][o] fp32 -> Wt[l][e][o][i] fp16 (transpose+convert) ----------
__global__ __launch_bounds__(256) void convert_w(
    const float* __restrict__ w0, const float* __restrict__ w1,
    const float* __restrict__ w2, const float* __restrict__ wo,
    f16* __restrict__ Wt)
{
    __shared__ float tile[32][33];
    int b  = blockIdx.x;            // m*256 + bi*16 + bj
    int m  = b >> 8;                // 0..31  (layer*8 + expert)
    int bi = (b >> 4) & 15;
    int bj = b & 15;
    int layer = m >> 3;
    const float* src =
        (layer == 0 ? w0 : layer == 1 ? w1 : layer == 2 ? w2 : wo)
        + (size_t)(m & 7) * DIM * DIM;
    f16* dst = Wt + (size_t)m * DIM * DIM;
    int tx = threadIdx.x & 31, ty = threadIdx.x >> 5;
#pragma unroll
    for (int r = 0; r < 4; ++r)
        tile[ty + 8*r][tx] = src[(size_t)(bi*32 + ty + 8*r) * DIM + bj*32 + tx];
    __syncthreads();
#pragma unroll
    for (int r = 0; r < 4; ++r)
        dst[(size_t)(bj*32 + ty + 8*r) * DIM + bi*32 + tx] = (f16)tile[tx][ty + 8*r];
}

// ---------- prep: alpha = softmax(x@gate_w + gate_b); xh = fp16(x) ----------
__global__ __launch_bounds__(256) void gate_kernel(
    const float* __restrict__ x, const float* __restrict__ gw,
    const float* __restrict__ gb, float* __restrict__ alpha,
    f16* __restrict__ xh)
{
    int tid = threadIdx.x, lane = tid & 63, wid = tid >> 6;
    int row = blockIdx.x * 4 + wid;           // one row per wave
    const float* xr = x + (size_t)row * DIM;
    float acc[8] = {0,0,0,0,0,0,0,0};
    float xv[8];
#pragma unroll
    for (int j = 0; j < 8; ++j) {
        int d = lane + 64*j;
        float v = xr[d];
        xv[j] = v;
        const float4* g = (const float4*)(gw + (size_t)d * 8);
        float4 g0 = g[0], g1 = g[1];
        acc[0] += v*g0.x; acc[1] += v*g0.y; acc[2] += v*g0.z; acc[3] += v*g0.w;
        acc[4] += v*g1.x; acc[5] += v*g1.y; acc[6] += v*g1.z; acc[7] += v*g1.w;
    }
#pragma unroll
    for (int mlane = 32; mlane >= 1; mlane >>= 1) {
#pragma unroll
        for (int k = 0; k < 8; ++k) acc[k] += __shfl_xor(acc[k], mlane, 64);
    }
#pragma unroll
    for (int k = 0; k < 8; ++k) acc[k] += gb[k];
    float mx = acc[0];
#pragma unroll
    for (int k = 1; k < 8; ++k) mx = fmaxf(mx, acc[k]);
    float s = 0.f;
#pragma unroll
    for (int k = 0; k < 8; ++k) { acc[k] = __expf(acc[k] - mx); s += acc[k]; }
    float inv = 1.0f / s;
    if (lane == 0) {
        float4 a0 = {acc[0]*inv, acc[1]*inv, acc[2]*inv, acc[3]*inv};
        float4 a1 = {acc[4]*inv, acc[5]*inv, acc[6]*inv, acc[7]*inv};
        *(float4*)(alpha + (size_t)row*8)     = a0;
        *(float4*)(alpha + (size_t)row*8 + 4) = a1;
    }
#pragma unroll
    for (int j = 0; j < 8; ++j)
        xh[(size_t)row * DIM + lane + 64*j] = (f16)xv[j];
}

// ---------- fused MoIE layer: out = [relu]( sum_e alpha_e * (A @ W_e) + sum_e alpha_e b_e ) ----------
// ks outer / experts inner: A-tile staged once per ks, A-frags held in regs across 8 experts,
// alpha folded into A-frags (f16 pk_mul). Double-buffered A (per-ks) and B (per-step).
template<int RELU, int OUTF32>
__global__ __launch_bounds__(256, 4) void moie_gemm(
    const f16*  __restrict__ A,      // [16384][512] fp16
    const f16*  __restrict__ Wt,     // [8][512 o][512 i] fp16 (this layer)
    const float* __restrict__ alpha, // [16384][8]
    const float* __restrict__ bias,  // [8][512]
    f16*  __restrict__ Hout,
    float* __restrict__ Fout)
{
    __shared__ __align__(16) f16 Abuf[2][BM*BK];   // 2 x 8KB
    __shared__ __align__(16) f16 Bbuf[2][BN*BK];   // 2 x 4KB
    __shared__ float alpha_s[BM*9];
    __shared__ float bias_s[NEXP*BN];

    int bid = blockIdx.x;
    int cb = bid >> 7, rb = bid & 127;   // grid 1024 = 8 cb x 128 rb
    int rowBase = rb * BM, colBase = cb * BN;
    int tid = threadIdx.x, lane = tid & 63, wid = tid >> 6;
    int wm = wid >> 1, wn = wid & 1;     // wave tile 64x32

    for (int i = tid; i < BM*NEXP; i += 256)
        alpha_s[(i >> 3)*9 + (i & 7)] = alpha[(size_t)(rowBase + (i >> 3))*8 + (i & 7)];
    for (int i = tid; i < NEXP*BN; i += 256)
        bias_s[i] = bias[(i >> 6)*DIM + colBase + (i & 63)];

    // staging geometry (validated swizzle): source granule sg, read granule kg
    int sg = ((lane & 3) ^ ((lane >> 2) & 3)) * 8;
    const f16* aSrc = A  + (size_t)(rowBase + wid*32 + (lane >> 2)) * DIM + sg;
    const f16* bSrc = Wt + (size_t)(colBase + wid*16 + (lane >> 2)) * DIM + sg;
    f16* aD[2] = { Abuf[0] + wid*1024, Abuf[1] + wid*1024 };   // + second line at +512
    f16* bD[2] = { Bbuf[0] + wid*512,  Bbuf[1] + wid*512 };

    int kg  = ((lane >> 4) ^ (lane & 3)) * 8;
    int aOff = (wm*64 + (lane & 15)) * BK + kg;
    int bOff = (wn*32 + (lane & 15)) * BK + kg;

    // prologue staging: A(ks=0), B(t=0 : e=0,ks=0)
    GLOAD16(aSrc, aD[0]);
    GLOAD16(aSrc + 16*DIM, aD[0] + 512);
    GLOAD16(bSrc, bD[0]);
    __syncthreads();   // drains vmcnt(0): alpha_s/bias_s + prologue tiles ready

    // per-lane f16 alpha for A-frag scaling: af[i] lane row = wm*64+i*16+(lane&15)
    f16 salh[4][NEXP];
#pragma unroll
    for (int i = 0; i < 4; ++i) {
        int r = wm*64 + i*16 + (lane & 15);
#pragma unroll
        for (int e = 0; e < NEXP; ++e) salh[i][e] = (f16)alpha_s[r*9 + e];
    }

    f32x4 acc[4][2];
#pragma unroll
    for (int i = 0; i < 4; ++i) { acc[i][0] = (f32x4){0,0,0,0}; acc[i][1] = (f32x4){0,0,0,0}; }

    for (int ks = 0; ks < KSTEPS; ++ks) {
        // A-frags for this ks, held across all 8 experts
        f16x8 af[4];
        const f16* Ab = Abuf[ks & 1];
#pragma unroll
        for (int i = 0; i < 4; ++i) af[i] = *(const f16x8*)(Ab + aOff + i*512);
        if (ks + 1 < KSTEPS) {   // prefetch next A tile (covered by 8 expert steps)
            const f16* s = aSrc + (ks + 1)*BK;
            GLOAD16(s, aD[(ks + 1) & 1]);
            GLOAD16(s + 16*DIM, aD[(ks + 1) & 1] + 512);
        }
#pragma unroll
        for (int e = 0; e < NEXP; ++e) {
            // stage next B tile (buffer (e+1)&1), then compute current from e&1
            if (e < 7)
                GLOAD16(bSrc + (size_t)(e + 1)*WSTRIDE + ks*BK, bD[(e + 1) & 1]);
            else if (ks + 1 < KSTEPS)
                GLOAD16(bSrc + (ks + 1)*BK, bD[(e + 1) & 1]);

            const f16* Bb = Bbuf[e & 1];
            f16x8 bf0 = *(const f16x8*)(Bb + bOff);
            f16x8 bf1 = *(const f16x8*)(Bb + bOff + 512);

            __builtin_amdgcn_s_setprio(1);
#pragma unroll
            for (int i = 0; i < 4; ++i) {
                f16 s = salh[i][e];
                f16x8 sv = {s,s,s,s,s,s,s,s};
                f16x8 afs = af[i] * sv;       // fold alpha[row,e] into A-frag
                acc[i][0] = __builtin_amdgcn_mfma_f32_16x16x32_f16(afs, bf0, acc[i][0], 0, 0, 0);
                acc[i][1] = __builtin_amdgcn_mfma_f32_16x16x32_f16(afs, bf1, acc[i][1], 0, 0, 0);
            }
            __builtin_amdgcn_s_setprio(0);
            __syncthreads();   // vmcnt(0) drain: next tiles landed; current buffers free
        }
    }

    // epilogue: + sum_e alpha*bias, relu, store
#pragma unroll
    for (int i = 0; i < 4; ++i)
#pragma unroll
        for (int q = 0; q < 4; ++q) {
            int rloc = wm*64 + i*16 + (lane >> 4)*4 + q;
            size_t row = (size_t)(rowBase + rloc);
#pragma unroll
            for (int j = 0; j < 2; ++j) {
                int cloc = wn*32 + j*16 + (lane & 15);
                float v = acc[i][j][q];
#pragma unroll
                for (int e2 = 0; e2 < NEXP; ++e2)
                    v += alpha_s[rloc*9 + e2] * bias_s[e2*BN + cloc];
                if (RELU) v = fmaxf(v, 0.f);
                if (OUTF32) Fout[row*DIM + colBase + cloc] = v;
                else        Hout[row*DIM + colBase + cloc] = (f16)v;
            }
        }
}

extern "C" void kernel_launch(void* const* d_in, const int* in_sizes, int n_in,
                              void* d_out, int out_size, void* d_ws, size_t ws_size,
                              hipStream_t stream)
{
    const float* x  = (const float*)d_in[0];
    const float* gw = (const float*)d_in[1];
    const float* gb = (const float*)d_in[2];
    const float* w0 = (const float*)d_in[3];
    const float* b0 = (const float*)d_in[4];
    const float* w1 = (const float*)d_in[5];
    const float* b1 = (const float*)d_in[6];
    const float* w2 = (const float*)d_in[7];
    const float* b2 = (const float*)d_in[8];
    const float* wo = (const float*)d_in[9];
    const float* bo = (const float*)d_in[10];
    float* out = (float*)d_out;

    // workspace: Wt (32MB fp16, 4 layers) | alpha | h0 | h1
    char* ws = (char*)d_ws;
    const size_t wtBytes = (size_t)4 * NEXP * DIM * DIM * sizeof(f16);
    f16*   Wt    = (f16*)ws;
    float* alpha = (float*)(ws + wtBytes);
    f16*   h0    = (f16*)(ws + wtBytes + (size_t)NROWS*NEXP*sizeof(float));
    f16*   h1    = h0 + (size_t)NROWS * DIM;
    const size_t L = (size_t)NEXP * DIM * DIM;

    convert_w<<<8192, 256, 0, stream>>>(w0, w1, w2, wo, Wt);
    gate_kernel<<<NROWS/4, 256, 0, stream>>>(x, gw, gb, alpha, h0);

    moie_gemm<1,0><<<1024, 256, 0, stream>>>(h0, Wt,       alpha, b0, h1, nullptr);
    moie_gemm<1,0><<<1024, 256, 0, stream>>>(h1, Wt + L,   alpha, b1, h0, nullptr);
    moie_gemm<1,0><<<1024, 256, 0, stream>>>(h0, Wt + 2*L, alpha, b2, h1, nullptr);
    moie_gemm<0,1><<<1024, 256, 0, stream>>>(h1, Wt + 3*L, alpha, bo, nullptr, out);
}

// Round 3
// 816.606 us; speedup vs baseline: 5.7592x; 5.7592x over previous
//
#include <hip/hip_runtime.h>
#include <stdint.h>

typedef _Float16 f16;
typedef _Float16 f16x8 __attribute__((ext_vector_type(8)));
typedef float f32x4 __attribute__((ext_vector_type(4)));

#define NROWS 16384
#define DIM   512
#define NEXP  8
#define BM    128
#define BN    128
#define BK    32
#define NKS   (DIM/BK)          // 16 k-slices per expert
#define WSTRIDE (DIM*DIM)

// async global->LDS, 16B per lane, LDS dest = wave-uniform base + lane*16
#define GLOAD16(gp, lp) __builtin_amdgcn_global_load_lds( \
    (const __attribute__((address_space(1))) void*)(gp),  \
    (__attribute__((address_space(3))) void*)(lp), 16, 0, 0)

#define MFMA16(a,b,c) __builtin_amdgcn_mfma_f32_16x16x32_f16(a, b, c, 0, 0, 0)

// ---------- prep: W[l][e][i][o] fp32 -> Wt[l][e][o][i] fp16 (transpose+convert) ----------
__global__ __launch_bounds__(256) void convert_w(
    const float* __restrict__ w0, const float* __restrict__ w1,
    const float* __restrict__ w2, const float* __restrict__ wo,
    f16* __restrict__ Wt)
{
    __shared__ float tile[32][33];
    int b  = blockIdx.x;            // m*256 + bi*16 + bj
    int m  = b >> 8;                // 0..31  (layer*8 + expert)
    int bi = (b >> 4) & 15;
    int bj = b & 15;
    int layer = m >> 3;
    const float* src =
        (layer == 0 ? w0 : layer == 1 ? w1 : layer == 2 ? w2 : wo)
        + (size_t)(m & 7) * DIM * DIM;
    f16* dst = Wt + (size_t)m * DIM * DIM;
    int tx = threadIdx.x & 31, ty = threadIdx.x >> 5;
#pragma unroll
    for (int r = 0; r < 4; ++r)
        tile[ty + 8*r][tx] = src[(size_t)(bi*32 + ty + 8*r) * DIM + bj*32 + tx];
    __syncthreads();
#pragma unroll
    for (int r = 0; r < 4; ++r)
        dst[(size_t)(bj*32 + ty + 8*r) * DIM + bi*32 + tx] = (f16)tile[tx][ty + 8*r];
}

// ---------- prep: alpha = softmax(x@gate_w + gate_b); xh = fp16(x) ----------
__global__ __launch_bounds__(256) void gate_kernel(
    const float* __restrict__ x, const float* __restrict__ gw,
    const float* __restrict__ gb, float* __restrict__ alpha,
    f16* __restrict__ xh)
{
    int tid = threadIdx.x, lane = tid & 63, wid = tid >> 6;
    int row = blockIdx.x * 4 + wid;           // one row per wave
    const float* xr = x + (size_t)row * DIM;
    float acc[8] = {0,0,0,0,0,0,0,0};
    float xv[8];
#pragma unroll
    for (int j = 0; j < 8; ++j) {
        int d = lane + 64*j;
        float v = xr[d];
        xv[j] = v;
        const float4* g = (const float4*)(gw + (size_t)d * 8);
        float4 g0 = g[0], g1 = g[1];
        acc[0] += v*g0.x; acc[1] += v*g0.y; acc[2] += v*g0.z; acc[3] += v*g0.w;
        acc[4] += v*g1.x; acc[5] += v*g1.y; acc[6] += v*g1.z; acc[7] += v*g1.w;
    }
#pragma unroll
    for (int mlane = 32; mlane >= 1; mlane >>= 1) {
#pragma unroll
        for (int k = 0; k < 8; ++k) acc[k] += __shfl_xor(acc[k], mlane, 64);
    }
#pragma unroll
    for (int k = 0; k < 8; ++k) acc[k] += gb[k];
    float mx = acc[0];
#pragma unroll
    for (int k = 1; k < 8; ++k) mx = fmaxf(mx, acc[k]);
    float s = 0.f;
#pragma unroll
    for (int k = 0; k < 8; ++k) { acc[k] = __expf(acc[k] - mx); s += acc[k]; }
    float inv = 1.0f / s;
    if (lane == 0) {
        float4 a0 = {acc[0]*inv, acc[1]*inv, acc[2]*inv, acc[3]*inv};
        float4 a1 = {acc[4]*inv, acc[5]*inv, acc[6]*inv, acc[7]*inv};
        *(float4*)(alpha + (size_t)row*8)     = a0;
        *(float4*)(alpha + (size_t)row*8 + 4) = a1;
    }
#pragma unroll
    for (int j = 0; j < 8; ++j)
        xh[(size_t)row * DIM + lane + 64*j] = (f16)xv[j];
}

// ---------- fused MoIE layer as one GEMM: C = Atilde @ Wtilde ----------
// Atilde[b, e*512+k] = alpha[b,e]*A[b,k] (alpha folded into A-frags, never materialized).
// k-slice outer (A staged once per 8 expert sub-steps), experts inner.
// Double-buffered A and B, ONE barrier per sub-step (stage-next-before-compute).
template<int RELU, int OUTF32>
__global__ __launch_bounds__(512, 4) void moie_gemm(
    const f16*  __restrict__ A,      // [16384][512] fp16
    const f16*  __restrict__ Wt,     // [8][512 o][512 i] fp16 (this layer)
    const float* __restrict__ alpha, // [16384][8]
    const float* __restrict__ bias,  // [8][512]
    f16*  __restrict__ Hout,
    float* __restrict__ Fout)
{
    __shared__ __align__(16) f16 Abuf0[BM*BK], Abuf1[BM*BK];   // 2 x 8KB
    __shared__ __align__(16) f16 Bbuf0[BN*BK], Bbuf1[BN*BK];   // 2 x 8KB
    __shared__ float alpha_s[BM*9];
    __shared__ float bias_s[NEXP*BN];

    // XCD swizzle: 512 blocks, 64 consecutive swz-ids per XCD -> same cb per XCD (B L2-resident)
    int bid = blockIdx.x;
    int swz = (bid & 7) * 64 + (bid >> 3);
    int cb = swz >> 7, rb = swz & 127;
    int rowBase = rb * BM, colBase = cb * BN;
    int tid = threadIdx.x, lane = tid & 63, wid = tid >> 6;
    int wm = wid >> 1, wn = wid & 1;     // 4x2 waves, wave tile 32x64

    for (int i = tid; i < BM*NEXP; i += 512)
        alpha_s[(i >> 3)*9 + (i & 7)] = alpha[(size_t)(rowBase + (i >> 3))*8 + (i & 7)];
    for (int i = tid; i < NEXP*BN; i += 512)
        bias_s[i] = bias[(i >> 7)*DIM + colBase + (i & 127)];

    // staging: 512 threads stage a full 128x32 tile in ONE call: tid>>2 = row, tid&3 = granule.
    // XOR swizzle (validated R1): slot (r,g) holds global granule g^(r&3); source pre-swizzled.
    int srow = tid >> 2;
    int sg   = ((tid & 3) ^ (srow & 3)) * 8;
    const f16* aSrc = A  + (size_t)(rowBase + srow) * DIM + sg;
    const f16* bSrc = Wt + (size_t)(colBase + srow) * DIM + sg;
    f16* aD0 = Abuf0 + tid*8;  f16* aD1 = Abuf1 + tid*8;   // linear dest, tid*16B
    f16* bD0 = Bbuf0 + tid*8;  f16* bD1 = Bbuf1 + tid*8;

    // read side: row=(lane&15)+16*i(+wave off), slot granule = (lane>>4)^(row&3)
    int kg   = ((lane >> 4) ^ (lane & 3)) * 8;
    int aOff = (wm*32 + (lane & 15)) * BK + kg;
    int bOff = (wn*64 + (lane & 15)) * BK + kg;

    // prologue: stage (ss=0) A and (e=0,ss=0) B into buffer 0
    GLOAD16(aSrc, aD0);
    GLOAD16(bSrc, bD0);
    __syncthreads();   // vmcnt(0) drained by compiler; alpha_s/bias_s also ready

    // per-lane f16 alpha: af[i] lane holds row wm*32+i*16+(lane&15)
    f16 salh0[NEXP], salh1[NEXP];
#pragma unroll
    for (int e = 0; e < NEXP; ++e) {
        salh0[e] = (f16)alpha_s[(wm*32 +      (lane & 15))*9 + e];
        salh1[e] = (f16)alpha_s[(wm*32 + 16 + (lane & 15))*9 + e];
    }

    f32x4 acc[2][4];
#pragma unroll
    for (int i = 0; i < 2; ++i)
#pragma unroll
        for (int j = 0; j < 4; ++j) acc[i][j] = (f32x4){0.f,0.f,0.f,0.f};

    for (int ss = 0; ss < NKS; ++ss) {
        const f16* Ab = (ss & 1) ? Abuf1 : Abuf0;
        f16x8 af0 = *(const f16x8*)(Ab + aOff);
        f16x8 af1 = *(const f16x8*)(Ab + aOff + 16*BK);
        if (ss + 1 < NKS) {                 // prefetch next A slice (covered by 8 sub-steps)
            f16* an = ((ss + 1) & 1) ? aD1 : aD0;
            GLOAD16(aSrc + (ss + 1)*BK, an);
        }
#pragma unroll
        for (int e = 0; e < NEXP; ++e) {
            // stage next B tile into the other buffer (t = ss*8+e; t&1 == e&1)
            if (e < 7) {
                f16* bn = ((e + 1) & 1) ? bD1 : bD0;
                GLOAD16(bSrc + (size_t)(e + 1)*WSTRIDE + ss*BK, bn);
            } else if (ss + 1 < NKS) {
                GLOAD16(bSrc + (ss + 1)*BK, bD0);   // next t even -> buffer 0
            }
            const f16* Bb = (e & 1) ? Bbuf1 : Bbuf0;
            f16x8 bf0 = *(const f16x8*)(Bb + bOff);
            f16x8 bf1 = *(const f16x8*)(Bb + bOff + 16*BK);
            f16x8 bf2 = *(const f16x8*)(Bb + bOff + 32*BK);
            f16x8 bf3 = *(const f16x8*)(Bb + bOff + 48*BK);

            f16 s0 = salh0[e], s1 = salh1[e];
            f16x8 sv0 = {s0,s0,s0,s0,s0,s0,s0,s0};
            f16x8 sv1 = {s1,s1,s1,s1,s1,s1,s1,s1};
            f16x8 a0 = af0 * sv0;             // fold alpha[row,e] into A-frag (exact algebra)
            f16x8 a1 = af1 * sv1;
            acc[0][0] = MFMA16(a0, bf0, acc[0][0]);
            acc[0][1] = MFMA16(a0, bf1, acc[0][1]);
            acc[0][2] = MFMA16(a0, bf2, acc[0][2]);
            acc[0][3] = MFMA16(a0, bf3, acc[0][3]);
            acc[1][0] = MFMA16(a1, bf0, acc[1][0]);
            acc[1][1] = MFMA16(a1, bf1, acc[1][1]);
            acc[1][2] = MFMA16(a1, bf2, acc[1][2]);
            acc[1][3] = MFMA16(a1, bf3, acc[1][3]);
            __syncthreads();   // one drain per sub-step: next tile landed, current free
        }
    }

    // epilogue: + sum_e alpha*bias, relu, store
#pragma unroll
    for (int i = 0; i < 2; ++i)
#pragma unroll
        for (int q = 0; q < 4; ++q) {
            int rloc = wm*32 + i*16 + (lane >> 4)*4 + q;
            size_t row = (size_t)(rowBase + rloc);
#pragma unroll
            for (int j = 0; j < 4; ++j) {
                int cloc = wn*64 + j*16 + (lane & 15);
                float v = acc[i][j][q];
#pragma unroll
                for (int e2 = 0; e2 < NEXP; ++e2)
                    v += alpha_s[rloc*9 + e2] * bias_s[e2*BN + cloc];
                if (RELU) v = fmaxf(v, 0.f);
                if (OUTF32) Fout[row*DIM + colBase + cloc] = v;
                else        Hout[row*DIM + colBase + cloc] = (f16)v;
            }
        }
}

extern "C" void kernel_launch(void* const* d_in, const int* in_sizes, int n_in,
                              void* d_out, int out_size, void* d_ws, size_t ws_size,
                              hipStream_t stream)
{
    const float* x  = (const float*)d_in[0];
    const float* gw = (const float*)d_in[1];
    const float* gb = (const float*)d_in[2];
    const float* w0 = (const float*)d_in[3];
    const float* b0 = (const float*)d_in[4];
    const float* w1 = (const float*)d_in[5];
    const float* b1 = (const float*)d_in[6];
    const float* w2 = (const float*)d_in[7];
    const float* b2 = (const float*)d_in[8];
    const float* wo = (const float*)d_in[9];
    const float* bo = (const float*)d_in[10];
    float* out = (float*)d_out;

    // workspace: Wt (32MB fp16, 4 layers) | alpha | h0 | h1
    char* ws = (char*)d_ws;
    const size_t wtBytes = (size_t)4 * NEXP * DIM * DIM * sizeof(f16);
    f16*   Wt    = (f16*)ws;
    float* alpha = (float*)(ws + wtBytes);
    f16*   h0    = (f16*)(ws + wtBytes + (size_t)NROWS*NEXP*sizeof(float));
    f16*   h1    = h0 + (size_t)NROWS * DIM;
    const size_t L = (size_t)NEXP * DIM * DIM;

    convert_w<<<8192, 256, 0, stream>>>(w0, w1, w2, wo, Wt);
    gate_kernel<<<NROWS/4, 256, 0, stream>>>(x, gw, gb, alpha, h0);

    moie_gemm<1,0><<<512, 512, 0, stream>>>(h0, Wt,       alpha, b0, h1, nullptr);
    moie_gemm<1,0><<<512, 512, 0, stream>>>(h1, Wt + L,   alpha, b1, h0, nullptr);
    moie_gemm<1,0><<<512, 512, 0, stream>>>(h0, Wt + 2*L, alpha, b2, h1, nullptr);
    moie_gemm<0,1><<<512, 512, 0, stream>>>(h1, Wt + 3*L, alpha, bo, nullptr, out);
}

// Round 4
// 324.989 us; speedup vs baseline: 14.4711x; 2.5127x over previous
//
#include <hip/hip_runtime.h>
#include <stdint.h>

typedef _Float16 f16;
typedef _Float16 f16x8 __attribute__((ext_vector_type(8)));
typedef float f32x4 __attribute__((ext_vector_type(4)));

#define NROWS 16384
#define DIM   512
#define NEXP  8
#define BM    256
#define BN    128
#define BK    32
#define NKS   (DIM/BK)          // 16 k-slices per expert
#define WSTRIDE (DIM*DIM)

// async global->LDS, 16B per lane
#define GLOAD16(gp, lp) __builtin_amdgcn_global_load_lds( \
    (const __attribute__((address_space(1))) void*)(gp),  \
    (__attribute__((address_space(3))) void*)(lp), 16, 0, 0)

#define MFMA16(a,b,c) __builtin_amdgcn_mfma_f32_16x16x32_f16(a, b, c, 0, 0, 0)

// ---------- prep: W[l][e][i][o] fp32 -> Wt[l][e][o][i] fp16 ----------
__global__ __launch_bounds__(256) void convert_w(
    const float* __restrict__ w0, const float* __restrict__ w1,
    const float* __restrict__ w2, const float* __restrict__ wo,
    f16* __restrict__ Wt)
{
    __shared__ float tile[32][33];
    int b  = blockIdx.x;
    int m  = b >> 8;
    int bi = (b >> 4) & 15;
    int bj = b & 15;
    int layer = m >> 3;
    const float* src =
        (layer == 0 ? w0 : layer == 1 ? w1 : layer == 2 ? w2 : wo)
        + (size_t)(m & 7) * DIM * DIM;
    f16* dst = Wt + (size_t)m * DIM * DIM;
    int tx = threadIdx.x & 31, ty = threadIdx.x >> 5;
#pragma unroll
    for (int r = 0; r < 4; ++r)
        tile[ty + 8*r][tx] = src[(size_t)(bi*32 + ty + 8*r) * DIM + bj*32 + tx];
    __syncthreads();
#pragma unroll
    for (int r = 0; r < 4; ++r)
        dst[(size_t)(bj*32 + ty + 8*r) * DIM + bi*32 + tx] = (f16)tile[tx][ty + 8*r];
}

// ---------- prep: alpha = softmax(x@gate_w + gate_b); xh = fp16(x) ----------
__global__ __launch_bounds__(256) void gate_kernel(
    const float* __restrict__ x, const float* __restrict__ gw,
    const float* __restrict__ gb, float* __restrict__ alpha,
    f16* __restrict__ xh)
{
    int tid = threadIdx.x, lane = tid & 63, wid = tid >> 6;
    int row = blockIdx.x * 4 + wid;
    const float* xr = x + (size_t)row * DIM;
    float acc[8] = {0,0,0,0,0,0,0,0};
    float xv[8];
#pragma unroll
    for (int j = 0; j < 8; ++j) {
        int d = lane + 64*j;
        float v = xr[d];
        xv[j] = v;
        const float4* g = (const float4*)(gw + (size_t)d * 8);
        float4 g0 = g[0], g1 = g[1];
        acc[0] += v*g0.x; acc[1] += v*g0.y; acc[2] += v*g0.z; acc[3] += v*g0.w;
        acc[4] += v*g1.x; acc[5] += v*g1.y; acc[6] += v*g1.z; acc[7] += v*g1.w;
    }
#pragma unroll
    for (int mlane = 32; mlane >= 1; mlane >>= 1) {
#pragma unroll
        for (int k = 0; k < 8; ++k) acc[k] += __shfl_xor(acc[k], mlane, 64);
    }
#pragma unroll
    for (int k = 0; k < 8; ++k) acc[k] += gb[k];
    float mx = acc[0];
#pragma unroll
    for (int k = 1; k < 8; ++k) mx = fmaxf(mx, acc[k]);
    float s = 0.f;
#pragma unroll
    for (int k = 0; k < 8; ++k) { acc[k] = __expf(acc[k] - mx); s += acc[k]; }
    float inv = 1.0f / s;
    if (lane == 0) {
        float4 a0 = {acc[0]*inv, acc[1]*inv, acc[2]*inv, acc[3]*inv};
        float4 a1 = {acc[4]*inv, acc[5]*inv, acc[6]*inv, acc[7]*inv};
        *(float4*)(alpha + (size_t)row*8)     = a0;
        *(float4*)(alpha + (size_t)row*8 + 4) = a1;
    }
#pragma unroll
    for (int j = 0; j < 8; ++j)
        xh[(size_t)row * DIM + lane + 64*j] = (f16)xv[j];
}

// ---------- fused MoIE layer as one M=16384,N=512,K=4096 GEMM ----------
// alpha folded into A-frags per (ks,e). Counted-vmcnt pipeline (T3+T4):
// B ring-4 (issue distance 3), A double-buffer, never drain vmcnt to 0 in-loop.
// One sub-step: [vmcnt(N); s_barrier; issue B(t+3)(+A at e0); ds_read; 16 MFMA].

// per-sub-step compute: bf from B ring slot SLOT, alpha column EIDX
#define ESTEP(WAITN, ISSUE, SLOT, EIDX) \
    asm volatile("s_waitcnt vmcnt(" #WAITN ")" ::: "memory"); \
    __builtin_amdgcn_s_barrier(); \
    ISSUE \
    { const f16* Bb = Ball + (SLOT)*4096 + bOff; \
      f16x8 bf0 = *(const f16x8*)(Bb); \
      f16x8 bf1 = *(const f16x8*)(Bb + 16*BK); \
      f16x8 bf2 = *(const f16x8*)(Bb + 32*BK); \
      f16x8 bf3 = *(const f16x8*)(Bb + 48*BK); \
      f16 s0 = salh[0][EIDX], s1 = salh[1][EIDX], s2 = salh[2][EIDX], s3 = salh[3][EIDX]; \
      f16x8 a0 = af0 * (f16x8){s0,s0,s0,s0,s0,s0,s0,s0}; \
      f16x8 a1 = af1 * (f16x8){s1,s1,s1,s1,s1,s1,s1,s1}; \
      f16x8 a2 = af2 * (f16x8){s2,s2,s2,s2,s2,s2,s2,s2}; \
      f16x8 a3 = af3 * (f16x8){s3,s3,s3,s3,s3,s3,s3,s3}; \
      __builtin_amdgcn_s_setprio(1); \
      acc[0][0]=MFMA16(a0,bf0,acc[0][0]); acc[0][1]=MFMA16(a0,bf1,acc[0][1]); \
      acc[0][2]=MFMA16(a0,bf2,acc[0][2]); acc[0][3]=MFMA16(a0,bf3,acc[0][3]); \
      acc[1][0]=MFMA16(a1,bf0,acc[1][0]); acc[1][1]=MFMA16(a1,bf1,acc[1][1]); \
      acc[1][2]=MFMA16(a1,bf2,acc[1][2]); acc[1][3]=MFMA16(a1,bf3,acc[1][3]); \
      acc[2][0]=MFMA16(a2,bf0,acc[2][0]); acc[2][1]=MFMA16(a2,bf1,acc[2][1]); \
      acc[2][2]=MFMA16(a2,bf2,acc[2][2]); acc[2][3]=MFMA16(a2,bf3,acc[2][3]); \
      acc[3][0]=MFMA16(a3,bf0,acc[3][0]); acc[3][1]=MFMA16(a3,bf1,acc[3][1]); \
      acc[3][2]=MFMA16(a3,bf2,acc[3][2]); acc[3][3]=MFMA16(a3,bf3,acc[3][3]); \
      __builtin_amdgcn_s_setprio(0); }

#define LOADAF \
      af0 = *(const f16x8*)(Ab + aOff); \
      af1 = *(const f16x8*)(Ab + aOff + 16*BK); \
      af2 = *(const f16x8*)(Ab + aOff + 32*BK); \
      af3 = *(const f16x8*)(Ab + aOff + 48*BK);

template<int RELU, int OUTF32>
__global__ __launch_bounds__(512, 2) void moie_gemm(
    const f16*  __restrict__ A,      // [16384][512] fp16
    const f16*  __restrict__ Wt,     // [8][512 o][512 i] fp16 (this layer)
    const float* __restrict__ alpha, // [16384][8]
    const float* __restrict__ bias,  // [8][512]
    f16*  __restrict__ Hout,
    float* __restrict__ Fout)
{
    __shared__ __align__(16) f16 Abuf[2][BM*BK];   // 2 x 16KB
    __shared__ __align__(16) f16 Bbuf[4][BN*BK];   // 4 x 8KB ring
    __shared__ float alpha_s[BM*9];
    __shared__ float bias_s[NEXP*BN];

    // 256 blocks, XCD = bid&7: 32 consecutive swz ids per XCD -> shared cb panel in L2
    int bid = blockIdx.x;
    int swz = (bid & 7) * 32 + (bid >> 3);
    int cb = swz >> 6, rb = swz & 63;
    int rowBase = rb * BM, colBase = cb * BN;
    int tid = threadIdx.x, lane = tid & 63, wid = tid >> 6;
    int wm = wid >> 1, wn = wid & 1;     // 4x2 waves, wave tile 64x64

    for (int i = tid; i < BM*NEXP; i += 512)
        alpha_s[(i >> 3)*9 + (i & 7)] = alpha[(size_t)(rowBase + (i >> 3))*8 + (i & 7)];
    for (int i = tid; i < NEXP*BN; i += 512)
        bias_s[i] = bias[(i >> 7)*DIM + colBase + (i & 127)];

    // staging: thread t -> row t>>2 (call covers 128 rows), granule (t&3), XOR-swizzled source
    int srow = tid >> 2;
    int sg   = ((tid & 3) ^ (srow & 3)) * 8;
    const f16* aSrc = A  + (size_t)(rowBase + srow) * DIM + sg;
    const f16* bSrc = Wt + (size_t)(colBase + srow) * DIM + sg;
    f16* aD0  = Abuf[0] + tid*8;  f16* aD0b = Abuf[0] + 4096 + tid*8;
    f16* aD1  = Abuf[1] + tid*8;  f16* aD1b = Abuf[1] + 4096 + tid*8;
    f16* bD   = Bbuf[0] + tid*8;              // slot s dest = bD + s*4096
    const f16* Ball = Bbuf[0];

    int kg   = ((lane >> 4) ^ (lane & 3)) * 8;
    int aOff = (wm*64 + (lane & 15)) * BK + kg;
    int bOff = (wn*64 + (lane & 15)) * BK + kg;

    __syncthreads();   // alpha_s/bias_s visible; drains their global loads (vmcnt clean)

    // prologue: A(0) x2, B0,B1,B2  -> queue [Aa,Ab,B0,B1,B2]
    GLOAD16(aSrc, aD0); GLOAD16(aSrc + 128*DIM, aD0b);
    GLOAD16(bSrc,                bD);
    GLOAD16(bSrc +   (size_t)WSTRIDE, bD + 4096);
    GLOAD16(bSrc + 2*(size_t)WSTRIDE, bD + 2*4096);

    f16 salh[4][NEXP];
#pragma unroll
    for (int i = 0; i < 4; ++i) {
        int r = wm*64 + i*16 + (lane & 15);
#pragma unroll
        for (int e = 0; e < NEXP; ++e) salh[i][e] = (f16)alpha_s[r*9 + e];
    }

    f32x4 acc[4][4];
#pragma unroll
    for (int i = 0; i < 4; ++i)
#pragma unroll
        for (int j = 0; j < 4; ++j) acc[i][j] = (f32x4){0.f,0.f,0.f,0.f};

    for (int ss = 0; ss < NKS - 1; ++ss) {
        const f16* Ab = (ss & 1) ? Abuf[1] : Abuf[0];
        f16* an0 = (ss & 1) ? aD0  : aD1;
        f16* an1 = (ss & 1) ? aD0b : aD1b;
        const f16* aN = aSrc + (ss + 1)*BK;
        const f16* bB = bSrc + ss*BK;
        f16x8 af0, af1, af2, af3;
        // waits: [2,4,4,4,2,2,2,2]  (A counts as 2 loads, drained by e4's wait)
        ESTEP(2, { GLOAD16(bB + 3*(size_t)WSTRIDE, bD + 3*4096);
                   GLOAD16(aN, an0); GLOAD16(aN + 128*DIM, an1);
                   LOADAF }, 0, 0)
        ESTEP(4, { GLOAD16(bB + 4*(size_t)WSTRIDE, bD);          }, 1, 1)
        ESTEP(4, { GLOAD16(bB + 5*(size_t)WSTRIDE, bD + 4096);   }, 2, 2)
        ESTEP(4, { GLOAD16(bB + 6*(size_t)WSTRIDE, bD + 2*4096); }, 3, 3)
        ESTEP(2, { GLOAD16(bB + 7*(size_t)WSTRIDE, bD + 3*4096); }, 0, 4)
        ESTEP(2, { GLOAD16(bB + BK,                       bD);          }, 1, 5)
        ESTEP(2, { GLOAD16(bB + BK +   (size_t)WSTRIDE,   bD + 4096);   }, 2, 6)
        ESTEP(2, { GLOAD16(bB + BK + 2*(size_t)WSTRIDE,   bD + 2*4096); }, 3, 7)
    }
    {   // peeled last k-slice (ss = 15, odd): waits [2,2,2,2,2,2,1,0]
        const f16* Ab = Abuf[1];
        const f16* bB = bSrc + (NKS - 1)*BK;
        f16x8 af0, af1, af2, af3;
        ESTEP(2, { GLOAD16(bB + 3*(size_t)WSTRIDE, bD + 3*4096); LOADAF }, 0, 0)
        ESTEP(2, { GLOAD16(bB + 4*(size_t)WSTRIDE, bD);          }, 1, 1)
        ESTEP(2, { GLOAD16(bB + 5*(size_t)WSTRIDE, bD + 4096);   }, 2, 2)
        ESTEP(2, { GLOAD16(bB + 6*(size_t)WSTRIDE, bD + 2*4096); }, 3, 3)
        ESTEP(2, { GLOAD16(bB + 7*(size_t)WSTRIDE, bD + 3*4096); }, 0, 4)
        ESTEP(2, { }, 1, 5)
        ESTEP(1, { }, 2, 6)
        ESTEP(0, { }, 3, 7)
    }

    // epilogue: + sum_e alpha*bias, relu, store
#pragma unroll
    for (int i = 0; i < 4; ++i)
#pragma unroll
        for (int q = 0; q < 4; ++q) {
            int rloc = wm*64 + i*16 + (lane >> 4)*4 + q;
            size_t row = (size_t)(rowBase + rloc);
#pragma unroll
            for (int j = 0; j < 4; ++j) {
                int cloc = wn*64 + j*16 + (lane & 15);
                float v = acc[i][j][q];
#pragma unroll
                for (int e2 = 0; e2 < NEXP; ++e2)
                    v += alpha_s[rloc*9 + e2] * bias_s[e2*BN + cloc];
                if (RELU) v = fmaxf(v, 0.f);
                if (OUTF32) Fout[row*DIM + colBase + cloc] = v;
                else        Hout[row*DIM + colBase + cloc] = (f16)v;
            }
        }
}

extern "C" void kernel_launch(void* const* d_in, const int* in_sizes, int n_in,
                              void* d_out, int out_size, void* d_ws, size_t ws_size,
                              hipStream_t stream)
{
    const float* x  = (const float*)d_in[0];
    const float* gw = (const float*)d_in[1];
    const float* gb = (const float*)d_in[2];
    const float* w0 = (const float*)d_in[3];
    const float* b0 = (const float*)d_in[4];
    const float* w1 = (const float*)d_in[5];
    const float* b1 = (const float*)d_in[6];
    const float* w2 = (const float*)d_in[7];
    const float* b2 = (const float*)d_in[8];
    const float* wo = (const float*)d_in[9];
    const float* bo = (const float*)d_in[10];
    float* out = (float*)d_out;

    char* ws = (char*)d_ws;
    const size_t wtBytes = (size_t)4 * NEXP * DIM * DIM * sizeof(f16);
    f16*   Wt    = (f16*)ws;
    float* alpha = (float*)(ws + wtBytes);
    f16*   h0    = (f16*)(ws + wtBytes + (size_t)NROWS*NEXP*sizeof(float));
    f16*   h1    = h0 + (size_t)NROWS * DIM;
    const size_t L = (size_t)NEXP * DIM * DIM;

    convert_w<<<8192, 256, 0, stream>>>(w0, w1, w2, wo, Wt);
    gate_kernel<<<NROWS/4, 256, 0, stream>>>(x, gw, gb, alpha, h0);

    moie_gemm<1,0><<<256, 512, 0, stream>>>(h0, Wt,       alpha, b0, h1, nullptr);
    moie_gemm<1,0><<<256, 512, 0, stream>>>(h1, Wt + L,   alpha, b1, h0, nullptr);
    moie_gemm<1,0><<<256, 512, 0, stream>>>(h0, Wt + 2*L, alpha, b2, h1, nullptr);
    moie_gemm<0,1><<<256, 512, 0, stream>>>(h1, Wt + 3*L, alpha, bo, nullptr, out);
}